// Round 12
// baseline (1605.220 us; speedup 1.0000x reference)
//
#include <hip/hip_runtime.h>
#include <stdint.h>

#define T_STEPS 14
#define B_DIM   4096
#define I_DIM   2048
#define H_DIM   1024
#define O_DIM   128
#define K_TOT   3072   // I_DIM + H_DIM

// fixed-point scale 2^25: |w|max ~0.16 -> |W| ~5.1M, 3 signed base-256 digits exact
#define WSCALE_F 33554432.0f

typedef __bf16  bf16x8  __attribute__((ext_vector_type(8)));
typedef float   floatx4 __attribute__((ext_vector_type(4)));
typedef int     int4v   __attribute__((ext_vector_type(4)));
typedef int     int16v  __attribute__((ext_vector_type(16)));

__device__ __forceinline__ uint16_t f2bf_rne(float f) {
    uint32_t u = __float_as_uint(f);
    u += 0x7fffu + ((u >> 16) & 1u);
    return (uint16_t)(u >> 16);
}
__device__ __forceinline__ float bf2f(uint16_t h) {
    return __uint_as_float(((uint32_t)h) << 16);
}

// async global->LDS, 16B/lane (still used by out_gemm)
__device__ __forceinline__ void gload_lds16(const void* g, void* l) {
    __builtin_amdgcn_global_load_lds((__attribute__((address_space(1))) void*)g,
                                     (__attribute__((address_space(3))) void*)l, 16, 0, 0);
}

// ================= fragment-order layouts, BK=128 (validated r11) =================
// B digits: WB[nt(32)][ktw(24)][s(3)][kk(4)][lane(64)][16B]      (12 KB chunks)
// A spikes: Xall[t][mIdx(32)][ktx(16)][group(4)][kk(4)][lane(64)][16B]  (16 KB chunks)
// Z state:  Z[mIdx(32)][ktz(8)][group(4)][kk(4)][lane(64)][16B]          (16 KB chunks)
// element (row = group*32 + (lane&31), k = kt*128 + kk*32 + (lane>>5)*16 + j)

__global__ void split_w_kernel(const float* __restrict__ w_in, const float* __restrict__ w_rec,
                               int8_t* __restrict__ WB) {
    int idx = blockIdx.x * 256 + threadIdx.x;          // over H_DIM*K_TOT
    int h = idx / K_TOT;
    int k = idx - h * K_TOT;
    float w = (k < I_DIM) ? w_in[(size_t)h * I_DIM + k]
                          : w_rec[(size_t)h * H_DIM + (k - I_DIM)];
    int W  = __float2int_rn(w * WSCALE_F);
    int d0 = (int8_t)(W & 0xFF);
    int r1 = (W - d0) >> 8;
    int d1 = (int8_t)(r1 & 0xFF);
    int d2 = (r1 - d1) >> 8;                           // |d2| <= ~80
    int nt = h >> 5, n32 = h & 31;
    int ktw = k >> 7, k128 = k & 127;
    int kk = k128 >> 5, half = (k128 >> 4) & 1, j = k128 & 15;
    int lane = half * 32 + n32;
    size_t base = (size_t)(nt * 24 + ktw) * 12288 + kk * 1024 + lane * 16 + j;
    WB[base] = (int8_t)d0; WB[base + 4096] = (int8_t)d1; WB[base + 8192] = (int8_t)d2;
}

// ---------- out_w -> bf16 hi/mid/lo (validated) ----------
__global__ void split_ow_kernel(const float* __restrict__ out_w, uint16_t* __restrict__ OW3) {
    int idx = blockIdx.x * 256 + threadIdx.x;          // over O_DIM*H_DIM
    float w = out_w[idx];
    uint16_t hi = f2bf_rne(w);
    float r1 = w - bf2f(hi);
    uint16_t mid = f2bf_rne(r1);
    float r2 = r1 - bf2f(mid);
    uint16_t lo = f2bf_rne(r2);
    const size_t S = (size_t)O_DIM * H_DIM;
    OW3[idx] = hi; OW3[idx + S] = mid; OW3[idx + 2 * S] = lo;
}

// ---------- x fp32 -> i8, ALL timesteps, BK=128 fragment-order (validated r11) ----------
__global__ void cvt_x_kernel(const float* __restrict__ x, int8_t* __restrict__ xb) {
    size_t gid = (size_t)blockIdx.x * 256 + threadIdx.x;   // one 16B output granule each
    int g = (int)(gid & 1023);                             // granule within 16KB chunk
    size_t chunk = gid >> 10;                              // (t*32 + mIdx)*16 + kt
    int kt   = (int)(chunk & 15);
    int mIdx = (int)((chunk >> 4) & 31);
    int t    = (int)(chunk >> 9);
    int group = g >> 8, kk = (g >> 6) & 3, lane = g & 63;
    int half = lane >> 5, row32 = lane & 31;
    int b = mIdx * 128 + group * 32 + row32;
    int k = kt * 128 + kk * 32 + half * 16;
    const float4* src = (const float4*)(x + ((size_t)t * B_DIM + b) * I_DIM + k);
    union { int8_t bytes[16]; int4v v; } u;
#pragma unroll
    for (int q = 0; q < 4; ++q) {
        float4 f = src[q];
        u.bytes[q * 4 + 0] = (int8_t)(f.x > 0.5f);
        u.bytes[q * 4 + 1] = (int8_t)(f.y > 0.5f);
        u.bytes[q * 4 + 2] = (int8_t)(f.z > 0.5f);
        u.bytes[q * 4 + 3] = (int8_t)(f.w > 0.5f);
    }
    ((int4v*)xb)[gid] = u.v;
}

// ---------- one LIF step: NO LDS, NO barriers — direct global->register MFMA stream ----
// tile 128M x 32N, each wave owns one 32-row group; mfma_i32_32x32x32_i8, BK=128
// A frags are wave-private; B frags identical across the block's 4 waves -> L1 reuse.
__launch_bounds__(256, 4)
__global__ void lif_step_kernel(const int8_t* __restrict__ Xt,   // [32][16][16384] this step
                                const int8_t* __restrict__ Zin,  // [32][8][16384]
                                const int8_t* __restrict__ WB,   // packed digits
                                float2* __restrict__ VI,         // interleaved v,i [b][h]
                                int8_t* __restrict__ Zout,       // [32][8][16384]
                                uint16_t* __restrict__ Zbf, int t) {
    const int tid  = threadIdx.x;
    const int wave = tid >> 6, lane = tid & 63;
    const int lane32 = lane & 31, hl = lane >> 5;

    // XCD swizzle: consecutive bids vary nt -> each XCD's L2 holds 4 weight strips
    const int nt = blockIdx.x & 31, mIdx = blockIdx.x >> 5;
    const int mBase = mIdx * 128, nBase = nt * 32;

    int16v acc[3] = {};

    const int nIters = (t > 0) ? 24 : 16;   // z==0 at t==0: skip Z phase

    for (int kt = 0; kt < nIters; ++kt) {
        const int8_t* chunkA = (kt < 16)
            ? Xt  + ((size_t)mIdx * 16 + kt) * 16384
            : Zin + ((size_t)mIdx * 8 + (kt - 16)) * 16384;
        const int8_t* aPtr = chunkA + wave * 4096 + lane * 16;
        const int8_t* bPtr = WB + (size_t)(nt * 24 + kt) * 12288 + lane * 16;
#pragma unroll
        for (int kk = 0; kk < 4; ++kk) {
            int4v aF = *(const int4v*)(aPtr + kk * 1024);
            int4v b0 = *(const int4v*)(bPtr + kk * 1024);
            int4v b1 = *(const int4v*)(bPtr + 4096 + kk * 1024);
            int4v b2 = *(const int4v*)(bPtr + 8192 + kk * 1024);
            acc[0] = __builtin_amdgcn_mfma_i32_32x32x32_i8(aF, b0, acc[0], 0, 0, 0);
            acc[1] = __builtin_amdgcn_mfma_i32_32x32x32_i8(aF, b1, acc[1], 0, 0, 0);
            acc[2] = __builtin_amdgcn_mfma_i32_32x32x32_i8(aF, b2, acc[2], 0, 0, 0);
        }
    }

    // ---- LIF epilogue: C/D 32x32 layout col=lane32, row=(r&3)+8*(r>>2)+4*hl (validated) ----
    int8_t* zchunk = Zout + ((size_t)mIdx * 8 + (nt >> 2)) * 16384;
#pragma unroll
    for (int r = 0; r < 16; ++r) {
#pragma clang fp contract(off)
        // exact digit combine (|counts| < 2^24)
        float cur = (float)acc[2][r] * (1.0f / 512.0f)
                  + (float)acc[1][r] * (1.0f / 131072.0f)
                  + (float)acc[0][r] * (1.0f / 33554432.0f);
        int row = (r & 3) + 8 * (r >> 2) + 4 * hl;    // 0..31 (C/D layout)
        int b = mBase + wave * 32 + row;
        int h = nBase + lane32;
        size_t idx = (size_t)b * H_DIM + h;
        float v, ii;
        if (t == 0) { v = 0.0f; ii = 0.0f; }
        else        { float2 vi = VI[idx]; v = vi.x; ii = vi.y; }
        float v_dec = v + 0.1f * ((0.0f - v) + ii);   // v + DT*TAU_MEM_INV*((V_LEAK-v)+i)
        float i_dec = ii - 0.2f * ii;                 // i - DT*TAU_SYN_INV*i
        bool z = (v_dec > 1.0f);
        float2 vi_new;
        vi_new.x = z ? 0.0f : v_dec;                  // == (1-z)*v_dec + z*V_RESET exactly
        vi_new.y = i_dec + cur;
        VI[idx] = vi_new;
        if (t == T_STEPS - 1) {
            Zbf[idx] = z ? (uint16_t)0x3F80 : (uint16_t)0;
        } else {
            // [group=wave][kk=nt&3][lane'=(lane32>>4)*32+row][j=lane32&15]
            zchunk[wave * 4096 + (nt & 3) * 1024
                   + ((lane32 >> 4) * 32 + row) * 16 + (lane32 & 15)]
                = z ? (int8_t)1 : (int8_t)0;
        }
    }
}

// ---------- output GEMM: out = z_T @ out_w^T + out_b (bf16x3; validated) ----------
__launch_bounds__(256)
__global__ void out_gemm_kernel(const uint16_t* __restrict__ Zfin,  // [B][H_DIM] bf16
                                const uint16_t* __restrict__ OW3,   // [3][O_DIM][H_DIM] bf16
                                const float* __restrict__ out_b,
                                float* __restrict__ out) {
    __shared__ uint16_t sA[128 * 32];
    __shared__ uint16_t sB[3][128 * 32];

    const int tid  = threadIdx.x;
    const int wave = tid >> 6, lane = tid & 63;
    const int wm = wave >> 1, wn = wave & 1;
    const int quad = lane >> 4, col = lane & 15;

    const int mBase = blockIdx.x * 128;

    floatx4 acc[4][4] = {};

    const int sRowA = wave * 16 + (lane >> 2);
    const int sCol  = (lane & 3) * 8;

    for (int kt = 0; kt < H_DIM / 32; ++kt) {
        const int kb = kt * 32;
        __syncthreads();
#pragma unroll
        for (int j = 0; j < 2; ++j) {
            const uint16_t* g = Zfin + (size_t)(mBase + j * 64 + sRowA) * H_DIM + kb + sCol;
            gload_lds16(g, &sA[(j * 64 + wave * 16) * 32]);
        }
#pragma unroll
        for (int s = 0; s < 3; ++s) {
            const uint16_t* wsrc = OW3 + (size_t)s * O_DIM * H_DIM;
#pragma unroll
            for (int j = 0; j < 2; ++j) {
                const uint16_t* g = wsrc + (size_t)(j * 64 + sRowA) * H_DIM + kb + sCol;
                gload_lds16(g, &sB[s][(j * 64 + wave * 16) * 32]);
            }
        }
        __syncthreads();

        bf16x8 aF[4];
#pragma unroll
        for (int mi = 0; mi < 4; ++mi) {
            int row = wm * 64 + mi * 16 + col;
            aF[mi] = *reinterpret_cast<const bf16x8*>(&sA[row * 32 + quad * 8]);
        }
#pragma unroll
        for (int s = 0; s < 3; ++s) {
            bf16x8 bF[4];
#pragma unroll
            for (int ni = 0; ni < 4; ++ni) {
                int row = wn * 64 + ni * 16 + col;
                bF[ni] = *reinterpret_cast<const bf16x8*>(&sB[s][row * 32 + quad * 8]);
            }
#pragma unroll
            for (int mi = 0; mi < 4; ++mi)
#pragma unroll
                for (int ni = 0; ni < 4; ++ni)
                    acc[mi][ni] = __builtin_amdgcn_mfma_f32_16x16x32_bf16(
                        aF[mi], bF[ni], acc[mi][ni], 0, 0, 0);
        }
    }

    {
#pragma clang fp contract(off)
#pragma unroll
        for (int mi = 0; mi < 4; ++mi)
#pragma unroll
            for (int ni = 0; ni < 4; ++ni)
#pragma unroll
                for (int r = 0; r < 4; ++r) {
                    int b = mBase + wm * 64 + mi * 16 + quad * 4 + r;
                    int h = wn * 64 + ni * 16 + col;
                    out[(size_t)b * O_DIM + h] = acc[mi][ni][r] + out_b[h];
                }
    }
}

extern "C" void kernel_launch(void* const* d_in, const int* in_sizes, int n_in,
                              void* d_out, int out_size, void* d_ws, size_t ws_size,
                              hipStream_t stream) {
    const float* x     = (const float*)d_in[0];
    const float* w_in  = (const float*)d_in[1];
    const float* w_rec = (const float*)d_in[2];
    const float* out_w = (const float*)d_in[3];
    const float* out_b = (const float*)d_in[4];
    float* out = (float*)d_out;

    char* ws = (char*)d_ws;
    size_t off = 0;
    int8_t*   WB   = (int8_t*)(ws + off);   off += (size_t)3 * H_DIM * K_TOT;        // 9.4 MB
    uint16_t* OW3  = (uint16_t*)(ws + off); off += (size_t)3 * O_DIM * H_DIM * 2;    // 0.8 MB
    int8_t*   Xall = (int8_t*)(ws + off);   off += (size_t)T_STEPS * B_DIM * I_DIM;  // 117 MB
    uint16_t* Zbf  = (uint16_t*)(ws + off); off += (size_t)B_DIM * H_DIM * 2;        // 8 MB
    int8_t*   Z0   = (int8_t*)(ws + off);   off += (size_t)B_DIM * H_DIM;            // 4 MB
    int8_t*   Z1   = (int8_t*)(ws + off);   off += (size_t)B_DIM * H_DIM;            // 4 MB
    float2*   VI   = (float2*)(ws + off);   off += (size_t)B_DIM * H_DIM * 8;        // 32 MB

    split_w_kernel<<<(H_DIM * K_TOT) / 256, 256, 0, stream>>>(w_in, w_rec, WB);
    split_ow_kernel<<<(O_DIM * H_DIM) / 256, 256, 0, stream>>>(out_w, OW3);
    cvt_x_kernel<<<(int)(((size_t)T_STEPS * B_DIM * I_DIM / 16) / 256), 256, 0, stream>>>(x, Xall);

    int8_t* zbuf[2] = { Z0, Z1 };
    for (int t = 0; t < T_STEPS; ++t) {
        lif_step_kernel<<<dim3(1024), 256, 0, stream>>>(
            Xall + (size_t)t * 32 * 16 * 16384, zbuf[t & 1], WB, VI,
            zbuf[(t + 1) & 1], Zbf, t);
    }
    out_gemm_kernel<<<B_DIM / 128, 256, 0, stream>>>(Zbf, OW3, out_b, out);
}

// Round 13
// 1376.953 us; speedup vs baseline: 1.1658x; 1.1658x over previous
//
#include <hip/hip_runtime.h>
#include <stdint.h>

#define T_STEPS 14
#define B_DIM   4096
#define I_DIM   2048
#define H_DIM   1024
#define O_DIM   128
#define K_TOT   3072   // I_DIM + H_DIM

// fixed-point scale 2^25: |w|max ~0.16 -> |W| ~5.1M, 3 signed base-256 digits exact
#define WSCALE_F 33554432.0f

typedef __bf16  bf16x8  __attribute__((ext_vector_type(8)));
typedef float   floatx4 __attribute__((ext_vector_type(4)));
typedef int     int4v   __attribute__((ext_vector_type(4)));
typedef int     int16v  __attribute__((ext_vector_type(16)));

__device__ __forceinline__ uint16_t f2bf_rne(float f) {
    uint32_t u = __float_as_uint(f);
    u += 0x7fffu + ((u >> 16) & 1u);
    return (uint16_t)(u >> 16);
}
__device__ __forceinline__ float bf2f(uint16_t h) {
    return __uint_as_float(((uint32_t)h) << 16);
}

// async global->LDS, 16B/lane; LDS dest = wave-uniform base + lane*16 (implicit)
__device__ __forceinline__ void gload_lds16(const void* g, void* l) {
    __builtin_amdgcn_global_load_lds((__attribute__((address_space(1))) void*)g,
                                     (__attribute__((address_space(3))) void*)l, 16, 0, 0);
}

// ================= fragment-order layouts, BK=128 (validated r11) =================
// B digits: WB[nt(32)][ktw(24)][s(3)][kk(4)][lane(64)][16B]      (12 KB chunks)
// A spikes: Xall[t][mc(32)][ktx(16)][group(4)][kk(4)][lane(64)][16B]  (16 KB chunks)
// Z state:  Z[mc(32)][ktz(8)][group(4)][kk(4)][lane(64)][16B]          (16 KB chunks)
// element (row = group*32 + (lane&31), k = kt*128 + kk*32 + (lane>>5)*16 + j)

__global__ void split_w_kernel(const float* __restrict__ w_in, const float* __restrict__ w_rec,
                               int8_t* __restrict__ WB) {
    int idx = blockIdx.x * 256 + threadIdx.x;          // over H_DIM*K_TOT
    int h = idx / K_TOT;
    int k = idx - h * K_TOT;
    float w = (k < I_DIM) ? w_in[(size_t)h * I_DIM + k]
                          : w_rec[(size_t)h * H_DIM + (k - I_DIM)];
    int W  = __float2int_rn(w * WSCALE_F);
    int d0 = (int8_t)(W & 0xFF);
    int r1 = (W - d0) >> 8;
    int d1 = (int8_t)(r1 & 0xFF);
    int d2 = (r1 - d1) >> 8;                           // |d2| <= ~80
    int nt = h >> 5, n32 = h & 31;
    int ktw = k >> 7, k128 = k & 127;
    int kk = k128 >> 5, half = (k128 >> 4) & 1, j = k128 & 15;
    int lane = half * 32 + n32;
    size_t base = (size_t)(nt * 24 + ktw) * 12288 + kk * 1024 + lane * 16 + j;
    WB[base] = (int8_t)d0; WB[base + 4096] = (int8_t)d1; WB[base + 8192] = (int8_t)d2;
}

// ---------- out_w -> bf16 hi/mid/lo (validated) ----------
__global__ void split_ow_kernel(const float* __restrict__ out_w, uint16_t* __restrict__ OW3) {
    int idx = blockIdx.x * 256 + threadIdx.x;          // over O_DIM*H_DIM
    float w = out_w[idx];
    uint16_t hi = f2bf_rne(w);
    float r1 = w - bf2f(hi);
    uint16_t mid = f2bf_rne(r1);
    float r2 = r1 - bf2f(mid);
    uint16_t lo = f2bf_rne(r2);
    const size_t S = (size_t)O_DIM * H_DIM;
    OW3[idx] = hi; OW3[idx + S] = mid; OW3[idx + 2 * S] = lo;
}

// ---------- x fp32 -> i8, ALL timesteps, BK=128 fragment-order (validated r11) ----------
__global__ void cvt_x_kernel(const float* __restrict__ x, int8_t* __restrict__ xb) {
    size_t gid = (size_t)blockIdx.x * 256 + threadIdx.x;   // one 16B output granule each
    int g = (int)(gid & 1023);                             // granule within 16KB chunk
    size_t chunk = gid >> 10;                              // (t*32 + mc)*16 + kt
    int kt   = (int)(chunk & 15);
    int mc   = (int)((chunk >> 4) & 31);
    int t    = (int)(chunk >> 9);
    int group = g >> 8, kk = (g >> 6) & 3, lane = g & 63;
    int half = lane >> 5, row32 = lane & 31;
    int b = mc * 128 + group * 32 + row32;
    int k = kt * 128 + kk * 32 + half * 16;
    const float4* src = (const float4*)(x + ((size_t)t * B_DIM + b) * I_DIM + k);
    union { int8_t bytes[16]; int4v v; } u;
#pragma unroll
    for (int q = 0; q < 4; ++q) {
        float4 f = src[q];
        u.bytes[q * 4 + 0] = (int8_t)(f.x > 0.5f);
        u.bytes[q * 4 + 1] = (int8_t)(f.y > 0.5f);
        u.bytes[q * 4 + 2] = (int8_t)(f.z > 0.5f);
        u.bytes[q * 4 + 3] = (int8_t)(f.w > 0.5f);
    }
    ((int4v*)xb)[gid] = u.v;
}

// ---------- one LIF step: tile 256M x 32N, BK=128, 512 blocks = 2/CU ----------
// 4 waves, each owns 64 rows (2 m-groups) x full 32N: each B fragment read feeds
// 2 MFMAs -> B ds_read and B staging per unit work HALVED vs r11.
__launch_bounds__(256, 2)
__global__ void lif_step_kernel(const int8_t* __restrict__ Xt,   // [32][16][16384] this step
                                const int8_t* __restrict__ Zin,  // [32][8][16384]
                                const int8_t* __restrict__ WB,   // packed digits
                                float2* __restrict__ VI,         // interleaved v,i [b][h]
                                int8_t* __restrict__ Zout,       // [32][8][16384]
                                uint16_t* __restrict__ Zbf, int t) {
    __shared__ int8_t sA[32768];   // [wave(4)][mi(2)][kk(4)][lane(64)][16B]
    __shared__ int8_t sB[12288];   // [s(3)][kk(4)][lane(64)][16B]

    const int tid  = threadIdx.x;
    const int wave = tid >> 6, lane = tid & 63;
    const int lane32 = lane & 31, hl = lane >> 5;

    // XCD swizzle: consecutive bids vary nt -> each XCD's L2 holds 4 weight strips
    const int nt = blockIdx.x & 31, mIdx = blockIdx.x >> 5;   // mIdx in [0,16)
    const int mBase = mIdx * 256, nBase = nt * 32;

    // wave's global 128-row chunk and half-within-chunk
    const int chunkIdx = 2 * mIdx + (wave >> 1);
    const int halfSel  = wave & 1;          // which 8KB half of the 16KB chunk

    int16v acc[2][3] = {};                  // [mi][digit]

    const int nIters = (t > 0) ? 24 : 16;   // z==0 at t==0: skip Z phase

    for (int kt = 0; kt < nIters; ++kt) {
        __syncthreads();
        // ---- stage A: wave stages its own 8KB (2 m-groups x 4 kk) ----
        const int8_t* chunkA = (kt < 16)
            ? Xt  + ((size_t)chunkIdx * 16 + kt) * 16384
            : Zin + ((size_t)chunkIdx * 8 + (kt - 16)) * 16384;
        const int8_t* srcA = chunkA + halfSel * 8192;
        int8_t* dstA = &sA[wave * 8192];
#pragma unroll
        for (int j = 0; j < 8; ++j)
            gload_lds16(srcA + j * 1024 + lane * 16, dstA + j * 1024);
        // ---- stage B: 12KB chunk; each wave 3KB ----
        const int8_t* chunkB = WB + (size_t)(nt * 24 + kt) * 12288;
#pragma unroll
        for (int j = 0; j < 3; ++j) {
            const int seg = j * 4 + wave;
            gload_lds16(chunkB + seg * 1024 + lane * 16, &sB[seg * 1024]);
        }
        __syncthreads();
        // ---- compute: 4 kk x 3 s x 2 mi = 24 MFMA per wave, 20 ds_reads ----
#pragma unroll
        for (int kk = 0; kk < 4; ++kk) {
            int4v a0 = *(const int4v*)&sA[wave * 8192 + kk * 1024 + lane * 16];
            int4v a1 = *(const int4v*)&sA[wave * 8192 + 4096 + kk * 1024 + lane * 16];
#pragma unroll
            for (int s = 0; s < 3; ++s) {
                int4v bF = *(const int4v*)&sB[s * 4096 + kk * 1024 + lane * 16];
                acc[0][s] = __builtin_amdgcn_mfma_i32_32x32x32_i8(a0, bF, acc[0][s], 0, 0, 0);
                acc[1][s] = __builtin_amdgcn_mfma_i32_32x32x32_i8(a1, bF, acc[1][s], 0, 0, 0);
            }
        }
    }

    // ---- LIF epilogue: C/D 32x32 layout col=lane32, row=(r&3)+8*(r>>2)+4*hl ----
    int8_t* zchunk = Zout + ((size_t)chunkIdx * 8 + (nt >> 2)) * 16384;
#pragma unroll
    for (int mi = 0; mi < 2; ++mi)
#pragma unroll
        for (int r = 0; r < 16; ++r) {
#pragma clang fp contract(off)
            // exact digit combine (|counts| < 2^24)
            float cur = (float)acc[mi][2][r] * (1.0f / 512.0f)
                      + (float)acc[mi][1][r] * (1.0f / 131072.0f)
                      + (float)acc[mi][0][r] * (1.0f / 33554432.0f);
            int row = (r & 3) + 8 * (r >> 2) + 4 * hl;    // 0..31 (C/D layout)
            int b = mBase + wave * 64 + mi * 32 + row;
            int h = nBase + lane32;
            size_t idx = (size_t)b * H_DIM + h;
            float v, ii;
            if (t == 0) { v = 0.0f; ii = 0.0f; }
            else        { float2 vi = VI[idx]; v = vi.x; ii = vi.y; }
            float v_dec = v + 0.1f * ((0.0f - v) + ii);   // v + DT*TAU_MEM_INV*((V_LEAK-v)+i)
            float i_dec = ii - 0.2f * ii;                 // i - DT*TAU_SYN_INV*i
            bool z = (v_dec > 1.0f);
            float2 vi_new;
            vi_new.x = z ? 0.0f : v_dec;                  // == (1-z)*v_dec + z*V_RESET exactly
            vi_new.y = i_dec + cur;
            VI[idx] = vi_new;
            if (t == T_STEPS - 1) {
                Zbf[idx] = z ? (uint16_t)0x3F80 : (uint16_t)0;
            } else {
                // [group=(halfSel*2+mi)][kk=nt&3][lane'=(lane32>>4)*32+row][j=lane32&15]
                zchunk[(halfSel * 2 + mi) * 4096 + (nt & 3) * 1024
                       + ((lane32 >> 4) * 32 + row) * 16 + (lane32 & 15)]
                    = z ? (int8_t)1 : (int8_t)0;
            }
        }
}

// ---------- output GEMM: out = z_T @ out_w^T + out_b (bf16x3; validated) ----------
__launch_bounds__(256)
__global__ void out_gemm_kernel(const uint16_t* __restrict__ Zfin,  // [B][H_DIM] bf16
                                const uint16_t* __restrict__ OW3,   // [3][O_DIM][H_DIM] bf16
                                const float* __restrict__ out_b,
                                float* __restrict__ out) {
    __shared__ uint16_t sA[128 * 32];
    __shared__ uint16_t sB[3][128 * 32];

    const int tid  = threadIdx.x;
    const int wave = tid >> 6, lane = tid & 63;
    const int wm = wave >> 1, wn = wave & 1;
    const int quad = lane >> 4, col = lane & 15;

    const int mBase = blockIdx.x * 128;

    floatx4 acc[4][4] = {};

    const int sRowA = wave * 16 + (lane >> 2);
    const int sCol  = (lane & 3) * 8;

    for (int kt = 0; kt < H_DIM / 32; ++kt) {
        const int kb = kt * 32;
        __syncthreads();
#pragma unroll
        for (int j = 0; j < 2; ++j) {
            const uint16_t* g = Zfin + (size_t)(mBase + j * 64 + sRowA) * H_DIM + kb + sCol;
            gload_lds16(g, &sA[(j * 64 + wave * 16) * 32]);
        }
#pragma unroll
        for (int s = 0; s < 3; ++s) {
            const uint16_t* wsrc = OW3 + (size_t)s * O_DIM * H_DIM;
#pragma unroll
            for (int j = 0; j < 2; ++j) {
                const uint16_t* g = wsrc + (size_t)(j * 64 + sRowA) * H_DIM + kb + sCol;
                gload_lds16(g, &sB[s][(j * 64 + wave * 16) * 32]);
            }
        }
        __syncthreads();

        bf16x8 aF[4];
#pragma unroll
        for (int mi = 0; mi < 4; ++mi) {
            int row = wm * 64 + mi * 16 + col;
            aF[mi] = *reinterpret_cast<const bf16x8*>(&sA[row * 32 + quad * 8]);
        }
#pragma unroll
        for (int s = 0; s < 3; ++s) {
            bf16x8 bF[4];
#pragma unroll
            for (int ni = 0; ni < 4; ++ni) {
                int row = wn * 64 + ni * 16 + col;
                bF[ni] = *reinterpret_cast<const bf16x8*>(&sB[s][row * 32 + quad * 8]);
            }
#pragma unroll
            for (int mi = 0; mi < 4; ++mi)
#pragma unroll
                for (int ni = 0; ni < 4; ++ni)
                    acc[mi][ni] = __builtin_amdgcn_mfma_f32_16x16x32_bf16(
                        aF[mi], bF[ni], acc[mi][ni], 0, 0, 0);
        }
    }

    {
#pragma clang fp contract(off)
#pragma unroll
        for (int mi = 0; mi < 4; ++mi)
#pragma unroll
            for (int ni = 0; ni < 4; ++ni)
#pragma unroll
                for (int r = 0; r < 4; ++r) {
                    int b = mBase + wm * 64 + mi * 16 + quad * 4 + r;
                    int h = wn * 64 + ni * 16 + col;
                    out[(size_t)b * O_DIM + h] = acc[mi][ni][r] + out_b[h];
                }
    }
}

extern "C" void kernel_launch(void* const* d_in, const int* in_sizes, int n_in,
                              void* d_out, int out_size, void* d_ws, size_t ws_size,
                              hipStream_t stream) {
    const float* x     = (const float*)d_in[0];
    const float* w_in  = (const float*)d_in[1];
    const float* w_rec = (const float*)d_in[2];
    const float* out_w = (const float*)d_in[3];
    const float* out_b = (const float*)d_in[4];
    float* out = (float*)d_out;

    char* ws = (char*)d_ws;
    size_t off = 0;
    int8_t*   WB   = (int8_t*)(ws + off);   off += (size_t)3 * H_DIM * K_TOT;        // 9.4 MB
    uint16_t* OW3  = (uint16_t*)(ws + off); off += (size_t)3 * O_DIM * H_DIM * 2;    // 0.8 MB
    int8_t*   Xall = (int8_t*)(ws + off);   off += (size_t)T_STEPS * B_DIM * I_DIM;  // 117 MB
    uint16_t* Zbf  = (uint16_t*)(ws + off); off += (size_t)B_DIM * H_DIM * 2;        // 8 MB
    int8_t*   Z0   = (int8_t*)(ws + off);   off += (size_t)B_DIM * H_DIM;            // 4 MB
    int8_t*   Z1   = (int8_t*)(ws + off);   off += (size_t)B_DIM * H_DIM;            // 4 MB
    float2*   VI   = (float2*)(ws + off);   off += (size_t)B_DIM * H_DIM * 8;        // 32 MB

    split_w_kernel<<<(H_DIM * K_TOT) / 256, 256, 0, stream>>>(w_in, w_rec, WB);
    split_ow_kernel<<<(O_DIM * H_DIM) / 256, 256, 0, stream>>>(out_w, OW3);
    cvt_x_kernel<<<(int)(((size_t)T_STEPS * B_DIM * I_DIM / 16) / 256), 256, 0, stream>>>(x, Xall);

    int8_t* zbuf[2] = { Z0, Z1 };
    for (int t = 0; t < T_STEPS; ++t) {
        lif_step_kernel<<<dim3(512), 256, 0, stream>>>(
            Xall + (size_t)t * 32 * 16 * 16384, zbuf[t & 1], WB, VI,
            zbuf[(t + 1) & 1], Zbf, t);
    }
    out_gemm_kernel<<<B_DIM / 128, 256, 0, stream>>>(Zbf, OW3, out_b, out);
}

// Round 14
// 1359.808 us; speedup vs baseline: 1.1805x; 1.0126x over previous
//
#include <hip/hip_runtime.h>
#include <stdint.h>

#define T_STEPS 14
#define B_DIM   4096
#define I_DIM   2048
#define H_DIM   1024
#define O_DIM   128
#define K_TOT   3072   // I_DIM + H_DIM

// fixed-point scale 2^25: |w|max ~0.16 -> |W| ~5.1M, 3 signed base-256 digits exact
#define WSCALE_F 33554432.0f

typedef __bf16  bf16x8  __attribute__((ext_vector_type(8)));
typedef float   floatx4 __attribute__((ext_vector_type(4)));
typedef int     int4v   __attribute__((ext_vector_type(4)));
typedef int     int16v  __attribute__((ext_vector_type(16)));

__device__ __forceinline__ uint16_t f2bf_rne(float f) {
    uint32_t u = __float_as_uint(f);
    u += 0x7fffu + ((u >> 16) & 1u);
    return (uint16_t)(u >> 16);
}
__device__ __forceinline__ float bf2f(uint16_t h) {
    return __uint_as_float(((uint32_t)h) << 16);
}

// async global->LDS, 16B/lane; LDS dest = wave-uniform base + lane*16 (implicit)
__device__ __forceinline__ void gload_lds16(const void* g, void* l) {
    __builtin_amdgcn_global_load_lds((__attribute__((address_space(1))) void*)g,
                                     (__attribute__((address_space(3))) void*)l, 16, 0, 0);
}

// ================= fragment-order layouts, BK=128 (validated r11) =================
// B digits: WB[nt(32)][ktw(24)][s(3)][kk(4)][lane(64)][16B]      (12 KB chunks)
// A spikes: Xall[t][mIdx(32)][ktx(16)][group(4)][kk(4)][lane(64)][16B]  (16 KB chunks)
// Z state:  Z[mIdx(32)][ktz(8)][group(4)][kk(4)][lane(64)][16B]          (16 KB chunks)
// element (row = group*32 + (lane&31), k = kt*128 + kk*32 + (lane>>5)*16 + j)

__global__ void split_w_kernel(const float* __restrict__ w_in, const float* __restrict__ w_rec,
                               int8_t* __restrict__ WB) {
    int idx = blockIdx.x * 256 + threadIdx.x;          // over H_DIM*K_TOT
    int h = idx / K_TOT;
    int k = idx - h * K_TOT;
    float w = (k < I_DIM) ? w_in[(size_t)h * I_DIM + k]
                          : w_rec[(size_t)h * H_DIM + (k - I_DIM)];
    int W  = __float2int_rn(w * WSCALE_F);
    int d0 = (int8_t)(W & 0xFF);
    int r1 = (W - d0) >> 8;
    int d1 = (int8_t)(r1 & 0xFF);
    int d2 = (r1 - d1) >> 8;                           // |d2| <= ~80
    int nt = h >> 5, n32 = h & 31;
    int ktw = k >> 7, k128 = k & 127;
    int kk = k128 >> 5, half = (k128 >> 4) & 1, j = k128 & 15;
    int lane = half * 32 + n32;
    size_t base = (size_t)(nt * 24 + ktw) * 12288 + kk * 1024 + lane * 16 + j;
    WB[base] = (int8_t)d0; WB[base + 4096] = (int8_t)d1; WB[base + 8192] = (int8_t)d2;
}

// ---------- out_w -> bf16 hi/mid/lo (validated) ----------
__global__ void split_ow_kernel(const float* __restrict__ out_w, uint16_t* __restrict__ OW3) {
    int idx = blockIdx.x * 256 + threadIdx.x;          // over O_DIM*H_DIM
    float w = out_w[idx];
    uint16_t hi = f2bf_rne(w);
    float r1 = w - bf2f(hi);
    uint16_t mid = f2bf_rne(r1);
    float r2 = r1 - bf2f(mid);
    uint16_t lo = f2bf_rne(r2);
    const size_t S = (size_t)O_DIM * H_DIM;
    OW3[idx] = hi; OW3[idx + S] = mid; OW3[idx + 2 * S] = lo;
}

// ---------- x fp32 -> i8, ALL timesteps, BK=128 fragment-order (validated r11) ----------
__global__ void cvt_x_kernel(const float* __restrict__ x, int8_t* __restrict__ xb) {
    size_t gid = (size_t)blockIdx.x * 256 + threadIdx.x;   // one 16B output granule each
    int g = (int)(gid & 1023);                             // granule within 16KB chunk
    size_t chunk = gid >> 10;                              // (t*32 + mIdx)*16 + kt
    int kt   = (int)(chunk & 15);
    int mIdx = (int)((chunk >> 4) & 31);
    int t    = (int)(chunk >> 9);
    int group = g >> 8, kk = (g >> 6) & 3, lane = g & 63;
    int half = lane >> 5, row32 = lane & 31;
    int b = mIdx * 128 + group * 32 + row32;
    int k = kt * 128 + kk * 32 + half * 16;
    const float4* src = (const float4*)(x + ((size_t)t * B_DIM + b) * I_DIM + k);
    union { int8_t bytes[16]; int4v v; } u;
#pragma unroll
    for (int q = 0; q < 4; ++q) {
        float4 f = src[q];
        u.bytes[q * 4 + 0] = (int8_t)(f.x > 0.5f);
        u.bytes[q * 4 + 1] = (int8_t)(f.y > 0.5f);
        u.bytes[q * 4 + 2] = (int8_t)(f.z > 0.5f);
        u.bytes[q * 4 + 3] = (int8_t)(f.w > 0.5f);
    }
    ((int4v*)xb)[gid] = u.v;
}

// ---------- one LIF step: tile 128M x 32N, BK=128, 1024 blocks = 4/CU (r11, best) ----------
// 4 waves, each owns one 32-row group x full 32N; mfma_i32_32x32x32_i8
__launch_bounds__(256, 4)
__global__ void lif_step_kernel(const int8_t* __restrict__ Xt,   // [32][16][16384] this step
                                const int8_t* __restrict__ Zin,  // [32][8][16384]
                                const int8_t* __restrict__ WB,   // packed digits
                                float2* __restrict__ VI,         // interleaved v,i [b][h]
                                int8_t* __restrict__ Zout,       // [32][8][16384]
                                uint16_t* __restrict__ Zbf, int t) {
    __shared__ int8_t sA[16384];   // [group(4)][kk(4)][lane(64)][16B]
    __shared__ int8_t sB[12288];   // [s(3)][kk(4)][lane(64)][16B]

    const int tid  = threadIdx.x;
    const int wave = tid >> 6, lane = tid & 63;
    const int lane32 = lane & 31, hl = lane >> 5;

    // XCD swizzle: consecutive bids vary nt -> each XCD's L2 holds 4 weight strips
    const int nt = blockIdx.x & 31, mIdx = blockIdx.x >> 5;
    const int mBase = mIdx * 128, nBase = nt * 32;

    int16v acc[3] = {};

    const int nIters = (t > 0) ? 24 : 16;   // z==0 at t==0: skip Z phase

    for (int kt = 0; kt < nIters; ++kt) {
        __syncthreads();
        // ---- stage A: 16KB chunk; each wave 4KB (segs j*4+wave) ----
        const int8_t* chunkA = (kt < 16)
            ? Xt  + ((size_t)mIdx * 16 + kt) * 16384
            : Zin + ((size_t)mIdx * 8 + (kt - 16)) * 16384;
#pragma unroll
        for (int j = 0; j < 4; ++j) {
            const int seg = j * 4 + wave;
            gload_lds16(chunkA + seg * 1024 + lane * 16, &sA[seg * 1024]);
        }
        // ---- stage B: 12KB chunk; each wave 3KB ----
        const int8_t* chunkB = WB + (size_t)(nt * 24 + kt) * 12288;
#pragma unroll
        for (int j = 0; j < 3; ++j) {
            const int seg = j * 4 + wave;
            gload_lds16(chunkB + seg * 1024 + lane * 16, &sB[seg * 1024]);
        }
        __syncthreads();
        // ---- compute: 4 kk x 3 s = 12 MFMA per wave ----
#pragma unroll
        for (int kk = 0; kk < 4; ++kk) {
            int4v aF = *(const int4v*)&sA[wave * 4096 + kk * 1024 + lane * 16];
#pragma unroll
            for (int s = 0; s < 3; ++s) {
                int4v bF = *(const int4v*)&sB[s * 4096 + kk * 1024 + lane * 16];
                acc[s] = __builtin_amdgcn_mfma_i32_32x32x32_i8(aF, bF, acc[s], 0, 0, 0);
            }
        }
    }

    // ---- LIF epilogue: C/D 32x32 layout col=lane32, row=(r&3)+8*(r>>2)+4*hl ----
    // z written in BK=128 fragment order: chunk ktz = nt>>2, kk = nt&3
    int8_t* zchunk = Zout + ((size_t)mIdx * 8 + (nt >> 2)) * 16384;
#pragma unroll
    for (int r = 0; r < 16; ++r) {
#pragma clang fp contract(off)
        // exact digit combine (|counts| < 2^24)
        float cur = (float)acc[2][r] * (1.0f / 512.0f)
                  + (float)acc[1][r] * (1.0f / 131072.0f)
                  + (float)acc[0][r] * (1.0f / 33554432.0f);
        int row = (r & 3) + 8 * (r >> 2) + 4 * hl;    // 0..31 (C/D layout)
        int b = mBase + wave * 32 + row;
        int h = nBase + lane32;
        size_t idx = (size_t)b * H_DIM + h;
        float v, ii;
        if (t == 0) { v = 0.0f; ii = 0.0f; }
        else        { float2 vi = VI[idx]; v = vi.x; ii = vi.y; }
        float v_dec = v + 0.1f * ((0.0f - v) + ii);   // v + DT*TAU_MEM_INV*((V_LEAK-v)+i)
        float i_dec = ii - 0.2f * ii;                 // i - DT*TAU_SYN_INV*i
        bool z = (v_dec > 1.0f);
        float2 vi_new;
        vi_new.x = z ? 0.0f : v_dec;                  // == (1-z)*v_dec + z*V_RESET exactly
        vi_new.y = i_dec + cur;
        VI[idx] = vi_new;
        if (t == T_STEPS - 1) {
            Zbf[idx] = z ? (uint16_t)0x3F80 : (uint16_t)0;
        } else {
            // [group=wave][kk=nt&3][lane'=(lane32>>4)*32+row][j=lane32&15]
            zchunk[wave * 4096 + (nt & 3) * 1024
                   + ((lane32 >> 4) * 32 + row) * 16 + (lane32 & 15)]
                = z ? (int8_t)1 : (int8_t)0;
        }
    }
}

// ---------- output GEMM: out = z_T @ out_w^T + out_b (bf16x3) ----------
// Repartitioned: M-tile 16 -> 256 blocks (full device) vs old 32 blocks (12% of CUs).
// Each block: 16M x 128N, K=1024. 4 waves each own a 32-wide N strip; the 3 bf16
// splits accumulate into the same acc (validated r1 fragment geometry).
__launch_bounds__(256)
__global__ void out_gemm_kernel(const uint16_t* __restrict__ Zfin,  // [B][H_DIM] bf16
                                const uint16_t* __restrict__ OW3,   // [3][O_DIM][H_DIM] bf16
                                const float* __restrict__ out_b,
                                float* __restrict__ out) {
    __shared__ uint16_t sA[16 * 32];        // 1 KB : [row(16)][k(32)]
    __shared__ uint16_t sB[3][128 * 32];    // 24 KB: [s][row(128)][k(32)]

    const int tid  = threadIdx.x;
    const int wave = tid >> 6, lane = tid & 63;
    const int quad = lane >> 4, col = lane & 15;

    const int mBase = blockIdx.x * 16;

    floatx4 acc[2] = {};

    const int ldRow = lane >> 2;        // 0..15
    const int ldCol = (lane & 3) * 8;   // element offset (x2B = 16B)

    for (int kt = 0; kt < H_DIM / 32; ++kt) {
        const int kb = kt * 32;
        __syncthreads();
        if (wave == 0) {
            const uint16_t* g = Zfin + (size_t)(mBase + ldRow) * H_DIM + kb + ldCol;
            gload_lds16(g, &sA[0]);
        }
#pragma unroll
        for (int s = 0; s < 3; ++s) {
            const uint16_t* wsrc = OW3 + (size_t)s * O_DIM * H_DIM;
#pragma unroll
            for (int j = 0; j < 2; ++j) {
                const int rseg = j * 4 + wave;   // 0..7, 16 rows each
                const uint16_t* g = wsrc + (size_t)(rseg * 16 + ldRow) * H_DIM + kb + ldCol;
                gload_lds16(g, &sB[s][rseg * 16 * 32]);
            }
        }
        __syncthreads();

        bf16x8 aF = *reinterpret_cast<const bf16x8*>(&sA[col * 32 + quad * 8]);
#pragma unroll
        for (int s = 0; s < 3; ++s) {
#pragma unroll
            for (int ni = 0; ni < 2; ++ni) {
                int row = wave * 32 + ni * 16 + col;
                bf16x8 bF = *reinterpret_cast<const bf16x8*>(&sB[s][row * 32 + quad * 8]);
                acc[ni] = __builtin_amdgcn_mfma_f32_16x16x32_bf16(aF, bF, acc[ni], 0, 0, 0);
            }
        }
    }

    {
#pragma clang fp contract(off)
#pragma unroll
        for (int ni = 0; ni < 2; ++ni)
#pragma unroll
            for (int r = 0; r < 4; ++r) {
                int b = mBase + quad * 4 + r;          // C/D: row = quad*4 + reg
                int h = wave * 32 + ni * 16 + col;     //      col = lane&15
                out[(size_t)b * O_DIM + h] = acc[ni][r] + out_b[h];
            }
    }
}

extern "C" void kernel_launch(void* const* d_in, const int* in_sizes, int n_in,
                              void* d_out, int out_size, void* d_ws, size_t ws_size,
                              hipStream_t stream) {
    const float* x     = (const float*)d_in[0];
    const float* w_in  = (const float*)d_in[1];
    const float* w_rec = (const float*)d_in[2];
    const float* out_w = (const float*)d_in[3];
    const float* out_b = (const float*)d_in[4];
    float* out = (float*)d_out;

    char* ws = (char*)d_ws;
    size_t off = 0;
    int8_t*   WB   = (int8_t*)(ws + off);   off += (size_t)3 * H_DIM * K_TOT;        // 9.4 MB
    uint16_t* OW3  = (uint16_t*)(ws + off); off += (size_t)3 * O_DIM * H_DIM * 2;    // 0.8 MB
    int8_t*   Xall = (int8_t*)(ws + off);   off += (size_t)T_STEPS * B_DIM * I_DIM;  // 117 MB
    uint16_t* Zbf  = (uint16_t*)(ws + off); off += (size_t)B_DIM * H_DIM * 2;        // 8 MB
    int8_t*   Z0   = (int8_t*)(ws + off);   off += (size_t)B_DIM * H_DIM;            // 4 MB
    int8_t*   Z1   = (int8_t*)(ws + off);   off += (size_t)B_DIM * H_DIM;            // 4 MB
    float2*   VI   = (float2*)(ws + off);   off += (size_t)B_DIM * H_DIM * 8;        // 32 MB

    split_w_kernel<<<(H_DIM * K_TOT) / 256, 256, 0, stream>>>(w_in, w_rec, WB);
    split_ow_kernel<<<(O_DIM * H_DIM) / 256, 256, 0, stream>>>(out_w, OW3);
    cvt_x_kernel<<<(int)(((size_t)T_STEPS * B_DIM * I_DIM / 16) / 256), 256, 0, stream>>>(x, Xall);

    int8_t* zbuf[2] = { Z0, Z1 };
    for (int t = 0; t < T_STEPS; ++t) {
        lif_step_kernel<<<dim3(1024), 256, 0, stream>>>(
            Xall + (size_t)t * 32 * 16 * 16384, zbuf[t & 1], WB, VI,
            zbuf[(t + 1) & 1], Zbf, t);
    }
    out_gemm_kernel<<<B_DIM / 16, 256, 0, stream>>>(Zbf, OW3, out_b, out);
}